// Round 1
// baseline (136.630 us; speedup 1.0000x reference)
//
#include <hip/hip_runtime.h>
#include <math.h>

// Problem sizes (fixed by the reference)
#define B   4
#define TQ  256
#define TV  1024
#define D   512
#define A   128

#define LOG2E     1.4426950408889634f
#define TWO_LOG2E 2.8853900817779268f
#define NEG_BIG_F (-1e9f)

#define QBLK (B * TQ / 8)   // 128 q-projection blocks
#define KBLK (B * TV / 8)   // 512 k-projection blocks

// ---------------------------------------------------------------------------
// Fused projection + exp(2x) for BOTH q and k.
//   q path: Eq[r, a]     = exp(2*(ctx[r,:]@Wq[:,a] + bq[a]))   [row-major]
//   k path: EkT[b, a, v] = exp(2*(inp[r,:]@Wk[:,a] + bk[a]))   [TRANSPOSED]
// ROUND-12 CHANGE: 512 threads (8 waves), d-split 8-way per wave (64 d each).
// Same instruction count / traffic as the 4-wave version, but 20 waves/CU
// (5/SIMD) instead of 10 (2.5/SIMD) -> scalar-load latency fully hidden.
// All 64 lanes of a wave share X addresses -> s_load_dwordx4. Lane owns an
// a-pair x 8 rows = 16 acc.
// ---------------------------------------------------------------------------
__global__ __launch_bounds__(512, 4) void proj_exp_kernel(
    const float* __restrict__ ctx, const float* __restrict__ inp,
    const float* __restrict__ Wq, const float* __restrict__ bq,
    const float* __restrict__ Wk, const float* __restrict__ bk,
    float* __restrict__ Eq, float* __restrict__ EkT) {
  __shared__ float ps[8][8][A];     // 32 KB (row j, wave g, a)
  __shared__ float es[A][9];        // 4.6 KB (transpose staging, +1 pad)

  bool isQ = blockIdx.x < QBLK;
  const float* X; const float* W; const float* bias; int r0;
  if (isQ) { X = ctx; W = Wq; bias = bq; r0 = blockIdx.x * 8; }
  else     { X = inp; W = Wk; bias = bk; r0 = (blockIdx.x - QBLK) * 8; }

  int tid = threadIdx.x;
  int ap = (tid & 63) * 2;      // a-pair base: 64 lanes cover a = 0..127
  int g  = tid >> 6;            // wave id 0..7  (wave-uniform)

  int dbase = __builtin_amdgcn_readfirstlane(g * 64);
  const float* Xr = X + (size_t)r0 * D + dbase;   // wave-uniform base
  const float* Wd = W + (size_t)dbase * A + ap;

  float2 acc[8];
#pragma unroll
  for (int j = 0; j < 8; ++j) acc[j] = make_float2(0.f, 0.f);

#pragma unroll 2
  for (int dd = 0; dd < 64; dd += 4) {
    float2 w0 = *(const float2*)(Wd + (size_t)(dd + 0) * A);
    float2 w1 = *(const float2*)(Wd + (size_t)(dd + 1) * A);
    float2 w2 = *(const float2*)(Wd + (size_t)(dd + 2) * A);
    float2 w3 = *(const float2*)(Wd + (size_t)(dd + 3) * A);
    float4 x[8];
#pragma unroll
    for (int j = 0; j < 8; ++j)
      x[j] = *(const float4*)(Xr + (size_t)j * D + dd);   // scalar s_load
#pragma unroll
    for (int j = 0; j < 8; ++j) {
      acc[j].x = fmaf(x[j].x, w0.x, acc[j].x);
      acc[j].y = fmaf(x[j].x, w0.y, acc[j].y);
      acc[j].x = fmaf(x[j].y, w1.x, acc[j].x);
      acc[j].y = fmaf(x[j].y, w1.y, acc[j].y);
      acc[j].x = fmaf(x[j].z, w2.x, acc[j].x);
      acc[j].y = fmaf(x[j].z, w2.y, acc[j].y);
      acc[j].x = fmaf(x[j].w, w3.x, acc[j].x);
      acc[j].y = fmaf(x[j].w, w3.y, acc[j].y);
    }
  }

#pragma unroll
  for (int j = 0; j < 8; ++j)
    *(float2*)&ps[j][g][ap] = acc[j];
  __syncthreads();

  // reduce 8 wave-partials: 512 threads, row j = tid>>6, a-pair per lane
  int j  = tid >> 6;            // 0..7
  int a2 = (tid & 63) * 2;
  float2 s0 = *(const float2*)&ps[j][0][a2];
  float2 s1 = *(const float2*)&ps[j][1][a2];
  float2 s2 = *(const float2*)&ps[j][2][a2];
  float2 s3 = *(const float2*)&ps[j][3][a2];
  float2 s4 = *(const float2*)&ps[j][4][a2];
  float2 s5 = *(const float2*)&ps[j][5][a2];
  float2 s6 = *(const float2*)&ps[j][6][a2];
  float2 s7 = *(const float2*)&ps[j][7][a2];
  float2 bz = *(const float2*)(bias + a2);
  float2 ev;
  ev.x = __builtin_amdgcn_exp2f(
      ((((s0.x + s1.x) + (s2.x + s3.x)) + ((s4.x + s5.x) + (s6.x + s7.x))) + bz.x) * TWO_LOG2E);
  ev.y = __builtin_amdgcn_exp2f(
      ((((s0.y + s1.y) + (s2.y + s3.y)) + ((s4.y + s5.y) + (s6.y + s7.y))) + bz.y) * TWO_LOG2E);

  if (isQ) {
    *(float2*)(Eq + (size_t)(r0 + j) * A + a2) = ev;   // coalesced per row
  } else {
    es[a2 + 0][j] = ev.x;
    es[a2 + 1][j] = ev.y;
    __syncthreads();
    int b  = r0 >> 10;          // TV == 1024
    int v0 = r0 & (TV - 1);
    for (int i = tid; i < A * 8; i += 512) {
      int aa = i >> 3, jj = i & 7;
      EkT[((size_t)b * A + aa) * TV + v0 + jj] = es[aa][jj];
    }
  }
}

// ---------------------------------------------------------------------------
// Scores + softmax (XCD-SWIZZLED block map): TWO q rows per block,
// 512 threads (8 waves), 512 blocks -> 16 waves/CU.
// Block map: b = blockIdx&3 (ties batch to XCD via round-robin dispatch so
// each XCD's 4MB L2 caches exactly one 2MB EkT[b] slice).
//   score[v] = sumV - 2 * sum_a v_a / (Eq[a]*EkT[a,v] + 1)
// ROUND-12 CHANGE: prefetch distance 1 -> 2. Two ping-pong register sets
// (P0/P1, 4 rows each); loads for rows i+8 are issued immediately AFTER the
// fmas that consume rows i (WAR on the same VGPRs keeps issue order), giving
// ~2 bodies (~380 cyc) of vmcnt slack instead of ~190. Tail prefetches read
// <=28KB past EkT[3] into the attn region of d_ws: in-bounds, discarded.
// ---------------------------------------------------------------------------
__global__ __launch_bounds__(512, 4) void score_softmax_kernel(
    const float* __restrict__ Eq, const float* __restrict__ EkT,
    const float* __restrict__ attn_v, const int* __restrict__ mask,
    float* __restrict__ attn) {
  __shared__ float redA[8], redB[8];
  __shared__ float bc[4];

  int tid = threadIdx.x;
  int v0  = (tid & 63) * 2 + (tid >> 6) * 128;  // wave-contiguous float2
  // XCD-aware decomposition: xcd = blk&7 -> b = xcd&3; pair = (xcd>>2)*64+grp
  int xcd = blockIdx.x & 7;
  int grp = blockIdx.x >> 3;           // 0..63
  int b   = xcd & 3;
  int pair = (xcd >> 2) * 64 + grp;    // 0..127
  int r0  = b * TQ + pair * 2;

  const float* eqA = Eq + (size_t)r0 * A;
  const float* eqB = eqA + A;

  float sumV = 0.f;
#pragma unroll 16
  for (int i = 0; i < A; ++i) sumV += attn_v[i];

  const float* ekb = EkT + (size_t)b * A * TV + v0;
  float2 tA = make_float2(0.f, 0.f);
  float2 tB = make_float2(0.f, 0.f);

  // preload rows 0..3 (P0) and 4..7 (P1)
  float2 p00 = *(const float2*)(ekb + (size_t)0 * TV);
  float2 p01 = *(const float2*)(ekb + (size_t)1 * TV);
  float2 p02 = *(const float2*)(ekb + (size_t)2 * TV);
  float2 p03 = *(const float2*)(ekb + (size_t)3 * TV);
  float2 p10 = *(const float2*)(ekb + (size_t)4 * TV);
  float2 p11 = *(const float2*)(ekb + (size_t)5 * TV);
  float2 p12 = *(const float2*)(ekb + (size_t)6 * TV);
  float2 p13 = *(const float2*)(ekb + (size_t)7 * TV);

  for (int i = 0; i < A; i += 8) {
    // ---------------- body A: rows i..i+3 (P0) ----------------
    {
      float av0 = attn_v[i + 0], av1 = attn_v[i + 1];
      float av2 = attn_v[i + 2], av3 = attn_v[i + 3];
      float qa0 = eqA[i + 0], qa1 = eqA[i + 1], qa2 = eqA[i + 2], qa3 = eqA[i + 3];
      float qb0 = eqB[i + 0], qb1 = eqB[i + 1], qb2 = eqB[i + 2], qb3 = eqB[i + 3];

      tA.x = fmaf(av0, __builtin_amdgcn_rcpf(fmaf(p00.x, qa0, 1.f)), tA.x);
      tA.y = fmaf(av0, __builtin_amdgcn_rcpf(fmaf(p00.y, qa0, 1.f)), tA.y);
      tB.x = fmaf(av0, __builtin_amdgcn_rcpf(fmaf(p00.x, qb0, 1.f)), tB.x);
      tB.y = fmaf(av0, __builtin_amdgcn_rcpf(fmaf(p00.y, qb0, 1.f)), tB.y);

      tA.x = fmaf(av1, __builtin_amdgcn_rcpf(fmaf(p01.x, qa1, 1.f)), tA.x);
      tA.y = fmaf(av1, __builtin_amdgcn_rcpf(fmaf(p01.y, qa1, 1.f)), tA.y);
      tB.x = fmaf(av1, __builtin_amdgcn_rcpf(fmaf(p01.x, qb1, 1.f)), tB.x);
      tB.y = fmaf(av1, __builtin_amdgcn_rcpf(fmaf(p01.y, qb1, 1.f)), tB.y);

      tA.x = fmaf(av2, __builtin_amdgcn_rcpf(fmaf(p02.x, qa2, 1.f)), tA.x);
      tA.y = fmaf(av2, __builtin_amdgcn_rcpf(fmaf(p02.y, qa2, 1.f)), tA.y);
      tB.x = fmaf(av2, __builtin_amdgcn_rcpf(fmaf(p02.x, qb2, 1.f)), tB.x);
      tB.y = fmaf(av2, __builtin_amdgcn_rcpf(fmaf(p02.y, qb2, 1.f)), tB.y);

      tA.x = fmaf(av3, __builtin_amdgcn_rcpf(fmaf(p03.x, qa3, 1.f)), tA.x);
      tA.y = fmaf(av3, __builtin_amdgcn_rcpf(fmaf(p03.y, qa3, 1.f)), tA.y);
      tB.x = fmaf(av3, __builtin_amdgcn_rcpf(fmaf(p03.x, qb3, 1.f)), tB.x);
      tB.y = fmaf(av3, __builtin_amdgcn_rcpf(fmaf(p03.y, qb3, 1.f)), tB.y);
    }
    // prefetch rows i+8..i+11 into P0 (consumed 2 bodies from now)
    p00 = *(const float2*)(ekb + (size_t)(i + 8) * TV);
    p01 = *(const float2*)(ekb + (size_t)(i + 9) * TV);
    p02 = *(const float2*)(ekb + (size_t)(i + 10) * TV);
    p03 = *(const float2*)(ekb + (size_t)(i + 11) * TV);

    // ---------------- body B: rows i+4..i+7 (P1) ----------------
    {
      float av0 = attn_v[i + 4], av1 = attn_v[i + 5];
      float av2 = attn_v[i + 6], av3 = attn_v[i + 7];
      float qa0 = eqA[i + 4], qa1 = eqA[i + 5], qa2 = eqA[i + 6], qa3 = eqA[i + 7];
      float qb0 = eqB[i + 4], qb1 = eqB[i + 5], qb2 = eqB[i + 6], qb3 = eqB[i + 7];

      tA.x = fmaf(av0, __builtin_amdgcn_rcpf(fmaf(p10.x, qa0, 1.f)), tA.x);
      tA.y = fmaf(av0, __builtin_amdgcn_rcpf(fmaf(p10.y, qa0, 1.f)), tA.y);
      tB.x = fmaf(av0, __builtin_amdgcn_rcpf(fmaf(p10.x, qb0, 1.f)), tB.x);
      tB.y = fmaf(av0, __builtin_amdgcn_rcpf(fmaf(p10.y, qb0, 1.f)), tB.y);

      tA.x = fmaf(av1, __builtin_amdgcn_rcpf(fmaf(p11.x, qa1, 1.f)), tA.x);
      tA.y = fmaf(av1, __builtin_amdgcn_rcpf(fmaf(p11.y, qa1, 1.f)), tA.y);
      tB.x = fmaf(av1, __builtin_amdgcn_rcpf(fmaf(p11.x, qb1, 1.f)), tB.x);
      tB.y = fmaf(av1, __builtin_amdgcn_rcpf(fmaf(p11.y, qb1, 1.f)), tB.y);

      tA.x = fmaf(av2, __builtin_amdgcn_rcpf(fmaf(p12.x, qa2, 1.f)), tA.x);
      tA.y = fmaf(av2, __builtin_amdgcn_rcpf(fmaf(p12.y, qa2, 1.f)), tA.y);
      tB.x = fmaf(av2, __builtin_amdgcn_rcpf(fmaf(p12.x, qb2, 1.f)), tB.x);
      tB.y = fmaf(av2, __builtin_amdgcn_rcpf(fmaf(p12.y, qb2, 1.f)), tB.y);

      tA.x = fmaf(av3, __builtin_amdgcn_rcpf(fmaf(p13.x, qa3, 1.f)), tA.x);
      tA.y = fmaf(av3, __builtin_amdgcn_rcpf(fmaf(p13.y, qa3, 1.f)), tA.y);
      tB.x = fmaf(av3, __builtin_amdgcn_rcpf(fmaf(p13.x, qb3, 1.f)), tB.x);
      tB.y = fmaf(av3, __builtin_amdgcn_rcpf(fmaf(p13.y, qb3, 1.f)), tB.y);
    }
    // prefetch rows i+12..i+15 into P1
    p10 = *(const float2*)(ekb + (size_t)(i + 12) * TV);
    p11 = *(const float2*)(ekb + (size_t)(i + 13) * TV);
    p12 = *(const float2*)(ekb + (size_t)(i + 14) * TV);
    p13 = *(const float2*)(ekb + (size_t)(i + 15) * TV);
  }

  int2 mk = *(const int2*)(mask + b * TV + v0);
  float mkx = (1.f - (float)mk.x) * NEG_BIG_F;
  float mky = (1.f - (float)mk.y) * NEG_BIG_F;
  float2 sA, sB;
  sA.x = sumV - 2.f * tA.x + mkx;
  sA.y = sumV - 2.f * tA.y + mky;
  sB.x = sumV - 2.f * tB.x + mkx;
  sB.y = sumV - 2.f * tB.y + mky;

  float mA = fmaxf(sA.x, sA.y);
  float mB = fmaxf(sB.x, sB.y);
  for (int off = 32; off > 0; off >>= 1) {
    mA = fmaxf(mA, __shfl_down(mA, off, 64));
    mB = fmaxf(mB, __shfl_down(mB, off, 64));
  }
  int w = tid >> 6;
  if ((tid & 63) == 0) { redA[w] = mA; redB[w] = mB; }
  __syncthreads();
  if (tid == 0) {
    float a = redA[0], bm = redB[0];
#pragma unroll
    for (int i = 1; i < 8; ++i) { a = fmaxf(a, redA[i]); bm = fmaxf(bm, redB[i]); }
    bc[0] = a; bc[1] = bm;
  }
  __syncthreads();
  float MA = bc[0], MB = bc[1];

  float2 eAv, eBv;
  eAv.x = __builtin_amdgcn_exp2f((sA.x - MA) * LOG2E);
  eAv.y = __builtin_amdgcn_exp2f((sA.y - MA) * LOG2E);
  eBv.x = __builtin_amdgcn_exp2f((sB.x - MB) * LOG2E);
  eBv.y = __builtin_amdgcn_exp2f((sB.y - MB) * LOG2E);
  float lA = eAv.x + eAv.y;
  float lB = eBv.x + eBv.y;
  for (int off = 32; off > 0; off >>= 1) {
    lA += __shfl_down(lA, off, 64);
    lB += __shfl_down(lB, off, 64);
  }
  __syncthreads();   // protect red[] before rewrite
  if ((tid & 63) == 0) { redA[w] = lA; redB[w] = lB; }
  __syncthreads();
  if (tid == 0) {
    float a = 0.f, bs = 0.f;
#pragma unroll
    for (int i = 0; i < 8; ++i) { a += redA[i]; bs += redB[i]; }
    bc[2] = a; bc[3] = bs;
  }
  __syncthreads();
  float iA = 1.f / bc[2];
  float iB = 1.f / bc[3];

  *(float2*)(attn + (size_t)r0 * TV + v0) =
      make_float2(eAv.x * iA, eAv.y * iA);
  *(float2*)(attn + (size_t)(r0 + 1) * TV + v0) =
      make_float2(eBv.x * iB, eBv.y * iB);
}

// ---------------------------------------------------------------------------
// out[b,q,:] = sum_v attn[b,q,v] * inputs[b,v,:]   -- NO ATOMICS.
// XCD-SWIZZLED 1-D block map: g = blk&15 -> b = g&3, dt = g>>2 (XCD blk&7
// then holds b=k&3, dt in {k>>2, k>>2+2}: 2 x 512KB X-slices, L2-resident);
// qt = blk>>4. 512 blocks x 512 thr -> 16 waves/CU.
// 8 waves own disjoint 128-v chunks; partials reduced through 32 KB LDS.
// (unchanged this round: prefetch slack already ~512 cyc per step)
// ---------------------------------------------------------------------------
__global__ __launch_bounds__(512, 4) void pv_kernel(
    const float* __restrict__ attn, const float* __restrict__ X,
    float* __restrict__ out) {
  __shared__ float lds[8 * 1024];    // 32 KB: attn tile, then 8 partial tiles
  int gsl = blockIdx.x & 15;         // (b, dt) slice group
  int b   = gsl & 3;
  int dt  = gsl >> 2;                // 0..3, d-slice of 128
  int qt  = blockIdx.x >> 4;         // 0..31
  int q0  = b * TQ + qt * 8;         // global row (b*TQ + q)
  int tid  = threadIdx.x;
  int w    = tid >> 6;               // wave 0..7 -> v range [w*128, w*128+128)
  int lane = tid & 63;
  int col  = lane & 31;              // float4 d-column
  int qh   = lane >> 5;              // 0..1 -> q rows qh*4 .. qh*4+3
  int d0 = dt * 128 + col * 4;

  // stage attn tile: 8 rows x 1024 v (float4, coalesced)
  {
    const float4* src = (const float4*)(attn + (size_t)q0 * TV);
    float4* dst = (float4*)lds;
    for (int i = tid; i < 8 * 256; i += 512) dst[i] = src[i];
  }
  __syncthreads();

  float4 acc[4];
#pragma unroll
  for (int j = 0; j < 4; ++j) acc[j] = make_float4(0.f, 0.f, 0.f, 0.f);

  int vbase = w * 128;
  const float* Xb = X + ((size_t)b * TV + vbase) * D + d0;
  const float* arow = &lds[(qh * 4) * 1024 + vbase];  // 4 rows, stride 1024

  float4 xc0 = *(const float4*)(Xb + (size_t)0 * D);
  float4 xc1 = *(const float4*)(Xb + (size_t)1 * D);
  float4 xc2 = *(const float4*)(Xb + (size_t)2 * D);
  float4 xc3 = *(const float4*)(Xb + (size_t)3 * D);

  for (int vi = 0; vi < 128; vi += 4) {
    float4 xn0, xn1, xn2, xn3;
    if (vi < 124) {
      const float* Xn = Xb + (size_t)(vi + 4) * D;
      xn0 = *(const float4*)(Xn + (size_t)0 * D);
      xn1 = *(const float4*)(Xn + (size_t)1 * D);
      xn2 = *(const float4*)(Xn + (size_t)2 * D);
      xn3 = *(const float4*)(Xn + (size_t)3 * D);
    }
#pragma unroll
    for (int j = 0; j < 4; ++j) {
      float4 av = *(const float4*)(arow + j * 1024 + vi);  // 2-addr bcast
      acc[j].x = fmaf(av.x, xc0.x, acc[j].x);
      acc[j].y = fmaf(av.x, xc0.y, acc[j].y);
      acc[j].z = fmaf(av.x, xc0.z, acc[j].z);
      acc[j].w = fmaf(av.x, xc0.w, acc[j].w);
      acc[j].x = fmaf(av.y, xc1.x, acc[j].x);
      acc[j].y = fmaf(av.y, xc1.y, acc[j].y);
      acc[j].z = fmaf(av.y, xc1.z, acc[j].z);
      acc[j].w = fmaf(av.y, xc1.w, acc[j].w);
      acc[j].x = fmaf(av.z, xc2.x, acc[j].x);
      acc[j].y = fmaf(av.z, xc2.y, acc[j].y);
      acc[j].z = fmaf(av.z, xc2.z, acc[j].z);
      acc[j].w = fmaf(av.z, xc2.w, acc[j].w);
      acc[j].x = fmaf(av.w, xc3.x, acc[j].x);
      acc[j].y = fmaf(av.w, xc3.y, acc[j].y);
      acc[j].z = fmaf(av.w, xc3.z, acc[j].z);
      acc[j].w = fmaf(av.w, xc3.w, acc[j].w);
    }
    xc0 = xn0; xc1 = xn1; xc2 = xn2; xc3 = xn3;
  }

  __syncthreads();   // everyone done READING the attn tile

  // write wave partials: lds[w][8 rows][32 float4 cols]
  {
    float4* pat = (float4*)lds + (size_t)w * 256;
#pragma unroll
    for (int j = 0; j < 4; ++j)
      pat[(qh * 4 + j) * 32 + col] = acc[j];
  }
  __syncthreads();

  // reduce 8 partials and store: 256 float4 outputs
  if (tid < 256) {
    int row = tid >> 5;            // 0..7
    int c   = tid & 31;            // 0..31
    const float4* p = (const float4*)lds + tid;  // == row*32 + c
    float4 r = p[0];
#pragma unroll
    for (int i = 1; i < 8; ++i) {
      float4 t = p[(size_t)i * 256];
      r.x += t.x; r.y += t.y; r.z += t.z; r.w += t.w;
    }
    *(float4*)(out + (size_t)(q0 + row) * D + dt * 128 + c * 4) = r;
  }
}

extern "C" void kernel_launch(void* const* d_in, const int* in_sizes, int n_in,
                              void* d_out, int out_size, void* d_ws, size_t ws_size,
                              hipStream_t stream) {
  const float* inputs  = (const float*)d_in[0];  // [B,TV,D]
  const float* context = (const float*)d_in[1];  // [B,TQ,D]
  const int*   mask    = (const int*)d_in[2];    // [B,TV]
  const float* Wk      = (const float*)d_in[3];  // [D,A]
  const float* bk      = (const float*)d_in[4];  // [A]
  const float* Wq      = (const float*)d_in[5];  // [D,A]
  const float* bq      = (const float*)d_in[6];  // [A]
  const float* attn_v  = (const float*)d_in[7];  // [A]
  float* out = (float*)d_out;                    // [B,TQ,D]

  // Workspace layout (fp32): Eq | EkT | attn  = 0.5MB + 2MB + 4MB
  float* Eq   = (float*)d_ws;             // [B*TQ, A]
  float* EkT  = Eq + B * TQ * A;          // [B, A, TV]  (transposed!)
  float* attn = EkT + (size_t)B * A * TV; // [B*TQ, TV]

  proj_exp_kernel<<<QBLK + KBLK, 512, 0, stream>>>(context, inputs, Wq, bq,
                                                   Wk, bk, Eq, EkT);
  score_softmax_kernel<<<B * TQ / 2, 512, 0, stream>>>(Eq, EkT, attn_v, mask,
                                                       attn);
  pv_kernel<<<512, 512, 0, stream>>>(attn, inputs, out);
}